// Round 4
// baseline (207.343 us; speedup 1.0000x reference)
//
#include <hip/hip_runtime.h>
#include <math.h>

#define SS 512
#define BB 512
#define TT 64
#define GRP 8

__device__ __forceinline__ float bl0(float x) {
    return __int_as_float(__builtin_amdgcn_readfirstlane(__float_as_int(x)));
}
__device__ __forceinline__ float rlane(float x, int i) {
    return __int_as_float(__builtin_amdgcn_readlane(__float_as_int(x), i));
}

// In-register matvec: acc_lane = sum_i p_i * e[i], p_i broadcast via v_readlane
// (compile-time lane index). 4 independent FMA chains; no LDS, no lgkmcnt.
__device__ __forceinline__ float matvec64(float p, const float* e) {
    float a0 = 0.f, a1 = 0.f, a2 = 0.f, a3 = 0.f;
    #pragma unroll
    for (int i = 0; i < 16; ++i) {
        a0 = fmaf(rlane(p, i     ), e[i     ], a0);
        a1 = fmaf(rlane(p, i + 16), e[i + 16], a1);
        a2 = fmaf(rlane(p, i + 32), e[i + 32], a2);
        a3 = fmaf(rlane(p, i + 48), e[i + 48], a3);
    }
    return (a0 + a1) + (a2 + a3);
}

// blocks [0,B): forward chains; [B,2B): backward chains; [2B,3B): numerator.
__global__ __launch_bounds__(64) void crf_chains(
    const float* __restrict__ em,      // S,B,T
    const int*   __restrict__ tags,    // S,B
    const int*   __restrict__ mask,    // S,B
    const float* __restrict__ start_t, // T
    const float* __restrict__ end_t,   // T
    const float* __restrict__ trans,   // T,T
    float* __restrict__ alpha_mid,     // B,T
    float* __restrict__ beta_mid,      // B,T
    float* __restrict__ num_ws)        // B
{
    const int lane = threadIdx.x;
    const int bid  = blockIdx.x;
    __shared__ float lds[TT * 65];     // bwd transpose staging only

    if (bid < BB) {
        // ---------------- forward: alpha_0 .. alpha_255 ----------------
        const int b = bid;
        const float* embase = em + (size_t)b * TT + lane;
        const int*   mkbase = mask + b;

        float e[TT];                    // e[i] = exp(trans[i][lane]) : column of E
        #pragma unroll
        for (int i = 0; i < TT; ++i)
            e[i] = __expf(trans[i * TT + lane]);

        float alpha = start_t[lane] + embase[0];

        float em0[GRP], em1[GRP];
        int   mk0[GRP], mk1[GRP];

        auto LOADF = [&](float* eb, int* mb, int g) {
            const int sb = 1 + g * GRP;                  // overrun stays < 512
            #pragma unroll
            for (int k = 0; k < GRP; ++k) {
                eb[k] = embase[(size_t)(sb + k) * BB * TT];
                mb[k] = mkbase[(sb + k) * BB];
            }
        };
        auto STEPSF = [&](const float* eb, const int* mb, bool lastg) {
            #pragma unroll
            for (int k = 0; k < GRP; ++k) {
                float off = bl0(alpha);
                float p   = __expf(alpha - off);
                float acc = matvec64(p, e);
                float na  = eb[k] + off + __logf(acc);
                int mk = mb[k];
                if (k == GRP - 1) mk = lastg ? 0 : mk;   // virtual masked step s=256
                alpha = mk ? na : alpha;
            }
        };

        LOADF(em0, mk0, 0);
        LOADF(em1, mk1, 1);
        for (int gg = 0; gg < 32; gg += 2) {
            STEPSF(em0, mk0, false);
            LOADF(em0, mk0, gg + 2);
            STEPSF(em1, mk1, gg + 1 == 31);
            LOADF(em1, mk1, gg + 3);
        }
        alpha_mid[(size_t)b * TT + lane] = alpha;

    } else if (bid < 2 * BB) {
        // ---------------- backward: beta_511 .. beta_255 ----------------
        const int b = bid - BB;
        const float* embase = em + (size_t)b * TT + lane;
        const int*   mkbase = mask + b;

        // row lane of E via LDS transpose (coalesced global, conflict-free LDS)
        for (int k = 0; k < TT; ++k)
            lds[k * 65 + lane] = trans[k * TT + lane];
        float e[TT];
        #pragma unroll
        for (int j = 0; j < TT; ++j)
            e[j] = __expf(lds[lane * 65 + j]);

        float beta = end_t[lane];

        float em0[GRP], em1[GRP];
        int   mk0[GRP], mk1[GRP];

        auto LOADB = [&](float* eb, int* mb, int g) {
            const int sb = 511 - g * GRP;                // overrun stays >= 0
            #pragma unroll
            for (int k = 0; k < GRP; ++k) {
                eb[k] = embase[(size_t)(sb - k) * BB * TT];
                mb[k] = mkbase[(sb - k) * BB];
            }
        };
        auto STEPSB = [&](const float* eb, const int* mb) {
            #pragma unroll
            for (int k = 0; k < GRP; ++k) {
                float qa  = eb[k] + beta;
                float off = bl0(qa);
                float q   = __expf(qa - off);
                float acc = matvec64(q, e);
                float nb  = off + __logf(acc);
                beta = mb[k] ? nb : beta;
            }
        };

        LOADB(em0, mk0, 0);
        LOADB(em1, mk1, 1);
        for (int gg = 0; gg < 32; gg += 2) {
            STEPSB(em0, mk0);
            LOADB(em0, mk0, gg + 2);
            STEPSB(em1, mk1);
            LOADB(em1, mk1, gg + 3);
        }
        beta_mid[(size_t)b * TT + lane] = beta;

    } else {
        // ---------------- numerator (tag-path score) ----------------
        const int b = bid - 2 * BB;
        float local = 0.f;
        int   mcnt  = 0;
        for (int s = lane; s < SS; s += 64) {
            int tag = tags[s * BB + b];
            int mk  = mask[s * BB + b];
            mcnt += mk;
            if (s == 0) {
                local += start_t[tag] + em[(size_t)b * TT + tag];
            } else if (mk) {
                int tp = tags[(s - 1) * BB + b];
                local += trans[tp * TT + tag] + em[(size_t)s * BB * TT + (size_t)b * TT + tag];
            }
        }
        #pragma unroll
        for (int d = 32; d > 0; d >>= 1) {
            local += __shfl_down(local, d, 64);
            mcnt  += __shfl_down(mcnt, d, 64);
        }
        if (lane == 0) {
            int last = tags[(mcnt - 1) * BB + b];
            num_ws[b] = local + end_t[last];
        }
    }
}

// Fused epilogue: per-batch denominator + llh + mean, one block of 8 waves.
// Wave w owns batches [w*64, (w+1)*64); per batch a 64-lane shuffle-LSE.
__global__ __launch_bounds__(512) void crf_finish(
    const float* __restrict__ alpha_mid,
    const float* __restrict__ beta_mid,
    const float* __restrict__ num_ws,
    float* __restrict__ out)
{
    const int lane = threadIdx.x & 63;
    const int w    = threadIdx.x >> 6;
    float acc = 0.f;
    for (int b = w * 64; b < (w + 1) * 64; ++b) {
        float v = alpha_mid[(size_t)b * TT + lane] + beta_mid[(size_t)b * TT + lane];
        float mx = v;
        #pragma unroll
        for (int d = 32; d > 0; d >>= 1) mx = fmaxf(mx, __shfl_xor(mx, d, 64));
        float s = __expf(v - mx);
        #pragma unroll
        for (int d = 32; d > 0; d >>= 1) s += __shfl_xor(s, d, 64);
        if (lane == 0) acc += num_ws[b] - (mx + __logf(s));
    }
    __shared__ float red[8];
    if (lane == 0) red[w] = acc;
    __syncthreads();
    if (threadIdx.x == 0) {
        float t = 0.f;
        #pragma unroll
        for (int i = 0; i < 8; ++i) t += red[i];
        out[0] = t / (float)BB;
    }
}

extern "C" void kernel_launch(void* const* d_in, const int* in_sizes, int n_in,
                              void* d_out, int out_size, void* d_ws, size_t ws_size,
                              hipStream_t stream) {
    const float* em    = (const float*)d_in[0];
    const int*   tags  = (const int*)d_in[1];
    const int*   mask  = (const int*)d_in[2];
    const float* st    = (const float*)d_in[3];
    const float* en    = (const float*)d_in[4];
    const float* tr    = (const float*)d_in[5];

    float* ws        = (float*)d_ws;
    float* alpha_mid = ws;
    float* beta_mid  = ws + (size_t)BB * TT;
    float* num_ws    = ws + (size_t)2 * BB * TT;

    crf_chains<<<3 * BB, 64, 0, stream>>>(em, tags, mask, st, en, tr,
                                          alpha_mid, beta_mid, num_ws);
    crf_finish<<<1, 512, 0, stream>>>(alpha_mid, beta_mid, num_ws, (float*)d_out);
}

// Round 5
// 157.396 us; speedup vs baseline: 1.3173x; 1.3173x over previous
//
#include <hip/hip_runtime.h>
#include <math.h>

#define SS 512
#define BB 512
#define TT 64
#define GRP 8

__device__ __forceinline__ float bl0(float x) {
    return __int_as_float(__builtin_amdgcn_readfirstlane(__float_as_int(x)));
}
__device__ __forceinline__ float rlane(float x, int i) {
    return __int_as_float(__builtin_amdgcn_readlane(__float_as_int(x), i));
}

// In-register matvec: acc_lane = sum_i p_i * e[i], p_i broadcast via v_readlane
// (compile-time lane index). 4 independent FMA chains; no LDS, no lgkmcnt.
__device__ __forceinline__ float matvec64(float p, const float* e) {
    float a0 = 0.f, a1 = 0.f, a2 = 0.f, a3 = 0.f;
    #pragma unroll
    for (int i = 0; i < 16; ++i) {
        a0 = fmaf(rlane(p, i     ), e[i     ], a0);
        a1 = fmaf(rlane(p, i + 16), e[i + 16], a1);
        a2 = fmaf(rlane(p, i + 32), e[i + 32], a2);
        a3 = fmaf(rlane(p, i + 48), e[i + 48], a3);
    }
    return (a0 + a1) + (a2 + a3);
}

// Exact power-of-2 renormalization: scale state so lane0 lands in [1,2);
// accumulate the (integer) exponent in Lexp. All-scalar except one v_mul.
__device__ __forceinline__ float renorm(float sel, int& Lexp) {
    int bits = __float_as_int(bl0(sel)) & 0x7f800000;
    bits = bits < 0x00800000 ? 0x00800000 : bits;   // guard denormal/zero
    bits = bits > 0x7e800000 ? 0x7e800000 : bits;   // guard inf/huge
    Lexp += (bits >> 23) - 127;
    float scale = __int_as_float(0x7f000000 - bits); // 2^-(E-127), exact
    return sel * scale;
}

// blocks [0,B): forward chains; [B,2B): backward chains; [2B,3B): numerator.
// One wave per block; (64,1) launch bounds so e[64] stays in VGPRs (no spill).
__global__ __launch_bounds__(64, 1) void crf_chains(
    const float* __restrict__ em,      // S,B,T
    const int*   __restrict__ tags,    // S,B
    const int*   __restrict__ mask,    // S,B
    const float* __restrict__ start_t, // T
    const float* __restrict__ end_t,   // T
    const float* __restrict__ trans,   // T,T
    float* __restrict__ alpha_mid,     // B,T
    float* __restrict__ beta_mid,      // B,T
    float* __restrict__ num_ws)        // B
{
    const int lane = threadIdx.x;
    const int bid  = blockIdx.x;
    __shared__ float lds[TT * 65];     // bwd transpose staging only

    if (bid < BB) {
        // ---------------- forward: alpha_0 .. alpha_255 (exp domain) ----------------
        const int b = bid;
        const float* embase = em + (size_t)b * TT + lane;
        const int*   mkbase = mask + b;

        float e[TT];                    // e[i] = exp(trans[i][lane]) : column of E
        #pragma unroll
        for (int i = 0; i < TT; ++i)
            e[i] = __expf(trans[i * TT + lane]);

        float av    = start_t[lane] + embase[0];
        float Lbase = bl0(av);
        float p     = __expf(av - Lbase);
        int   Lexp  = 0;

        float em0[GRP], em1[GRP];
        int   mk0[GRP], mk1[GRP];

        auto LOADF = [&](float* eb, int* mb, int g) {
            const int sb = 1 + g * GRP;                  // overrun stays < 512
            #pragma unroll
            for (int k = 0; k < GRP; ++k) {
                eb[k] = embase[(size_t)(sb + k) * BB * TT];
                mb[k] = mkbase[(sb + k) * BB];
            }
        };
        auto STEPSF = [&](const float* eb, const int* mb, bool lastg) {
            float Em[GRP];
            #pragma unroll
            for (int k = 0; k < GRP; ++k) Em[k] = __expf(eb[k]);  // off-spine
            #pragma unroll
            for (int k = 0; k < GRP; ++k) {
                float acc = matvec64(p, e);
                float t   = acc * Em[k];
                int mk = mb[k];
                if (k == GRP - 1) mk = lastg ? 0 : mk;   // virtual masked step s=256
                float sel = mk ? t : p;
                p = renorm(sel, Lexp);
            }
        };

        LOADF(em0, mk0, 0);
        LOADF(em1, mk1, 1);
        for (int gg = 0; gg < 32; gg += 2) {
            STEPSF(em0, mk0, false);
            LOADF(em0, mk0, gg + 2);
            STEPSF(em1, mk1, gg + 1 == 31);
            LOADF(em1, mk1, gg + 3);
        }
        double a = (double)Lbase + (double)Lexp * 0.6931471805599453 + (double)__logf(p);
        alpha_mid[(size_t)b * TT + lane] = (float)a;

    } else if (bid < 2 * BB) {
        // ---------------- backward: beta_511 .. beta_255 (exp domain) ----------------
        const int b = bid - BB;
        const float* embase = em + (size_t)b * TT + lane;
        const int*   mkbase = mask + b;

        // row lane of E via LDS transpose (coalesced global, conflict-free LDS)
        for (int k = 0; k < TT; ++k)
            lds[k * 65 + lane] = trans[k * TT + lane];
        float e[TT];
        #pragma unroll
        for (int j = 0; j < TT; ++j)
            e[j] = __expf(lds[lane * 65 + j]);

        float q    = __expf(end_t[lane]);
        int   Lexp = 0;

        float em0[GRP], em1[GRP];
        int   mk0[GRP], mk1[GRP];

        auto LOADB = [&](float* eb, int* mb, int g) {
            const int sb = 511 - g * GRP;                // overrun stays >= 0
            #pragma unroll
            for (int k = 0; k < GRP; ++k) {
                eb[k] = embase[(size_t)(sb - k) * BB * TT];
                mb[k] = mkbase[(sb - k) * BB];
            }
        };
        auto STEPSB = [&](const float* eb, const int* mb) {
            float Em[GRP];
            #pragma unroll
            for (int k = 0; k < GRP; ++k) Em[k] = __expf(eb[k]);  // off-spine
            #pragma unroll
            for (int k = 0; k < GRP; ++k) {
                float u   = q * Em[k];
                float acc = matvec64(u, e);
                float sel = mb[k] ? acc : q;
                q = renorm(sel, Lexp);
            }
        };

        LOADB(em0, mk0, 0);
        LOADB(em1, mk1, 1);
        for (int gg = 0; gg < 32; gg += 2) {
            STEPSB(em0, mk0);
            LOADB(em0, mk0, gg + 2);
            STEPSB(em1, mk1);
            LOADB(em1, mk1, gg + 3);
        }
        double bsum = (double)Lexp * 0.6931471805599453 + (double)__logf(q);
        beta_mid[(size_t)b * TT + lane] = (float)bsum;

    } else {
        // ---------------- numerator (tag-path score) ----------------
        const int b = bid - 2 * BB;
        float local = 0.f;
        int   mcnt  = 0;
        for (int s = lane; s < SS; s += 64) {
            int tag = tags[s * BB + b];
            int mk  = mask[s * BB + b];
            mcnt += mk;
            if (s == 0) {
                local += start_t[tag] + em[(size_t)b * TT + tag];
            } else if (mk) {
                int tp = tags[(s - 1) * BB + b];
                local += trans[tp * TT + tag] + em[(size_t)s * BB * TT + (size_t)b * TT + tag];
            }
        }
        #pragma unroll
        for (int d = 32; d > 0; d >>= 1) {
            local += __shfl_down(local, d, 64);
            mcnt  += __shfl_down(mcnt, d, 64);
        }
        if (lane == 0) {
            int last = tags[(mcnt - 1) * BB + b];
            num_ws[b] = local + end_t[last];
        }
    }
}

// per-batch denominator + llh: 64 blocks x 8 waves, one wave per batch.
__global__ __launch_bounds__(512) void crf_llh(
    const float* __restrict__ alpha_mid,
    const float* __restrict__ beta_mid,
    const float* __restrict__ num_ws,
    float* __restrict__ llh)
{
    const int lane = threadIdx.x & 63;
    const int b    = blockIdx.x * 8 + (threadIdx.x >> 6);
    float v = alpha_mid[(size_t)b * TT + lane] + beta_mid[(size_t)b * TT + lane];
    float mx = v;
    #pragma unroll
    for (int d = 32; d > 0; d >>= 1) mx = fmaxf(mx, __shfl_xor(mx, d, 64));
    float s = __expf(v - mx);
    #pragma unroll
    for (int d = 32; d > 0; d >>= 1) s += __shfl_xor(s, d, 64);
    if (lane == 0) llh[b] = num_ws[b] - (mx + __logf(s));
}

__global__ __launch_bounds__(512) void crf_mean(const float* __restrict__ llh,
                                               float* __restrict__ out)
{
    const int t = threadIdx.x;
    float v = llh[t];
    #pragma unroll
    for (int d = 32; d > 0; d >>= 1) v += __shfl_down(v, d, 64);
    __shared__ float red[8];
    if ((t & 63) == 0) red[t >> 6] = v;
    __syncthreads();
    if (t == 0) {
        float s = 0.f;
        #pragma unroll
        for (int w = 0; w < 8; ++w) s += red[w];
        out[0] = s / (float)BB;
    }
}

extern "C" void kernel_launch(void* const* d_in, const int* in_sizes, int n_in,
                              void* d_out, int out_size, void* d_ws, size_t ws_size,
                              hipStream_t stream) {
    const float* em    = (const float*)d_in[0];
    const int*   tags  = (const int*)d_in[1];
    const int*   mask  = (const int*)d_in[2];
    const float* st    = (const float*)d_in[3];
    const float* en    = (const float*)d_in[4];
    const float* tr    = (const float*)d_in[5];

    float* ws        = (float*)d_ws;
    float* alpha_mid = ws;
    float* beta_mid  = ws + (size_t)BB * TT;
    float* num_ws    = ws + (size_t)2 * BB * TT;
    float* llh       = ws + (size_t)2 * BB * TT + BB;

    crf_chains<<<3 * BB, 64, 0, stream>>>(em, tags, mask, st, en, tr,
                                          alpha_mid, beta_mid, num_ws);
    crf_llh<<<BB / 8, 512, 0, stream>>>(alpha_mid, beta_mid, num_ws, llh);
    crf_mean<<<1, 512, 0, stream>>>(llh, (float*)d_out);
}

// Round 7
// 155.375 us; speedup vs baseline: 1.3345x; 1.0130x over previous
//
#include <hip/hip_runtime.h>
#include <math.h>

#define SS 512
#define BB 512
#define TT 64
#define GRP 8

typedef float vf16 __attribute__((ext_vector_type(16)));
typedef float vf8  __attribute__((ext_vector_type(8)));
typedef int   vi8  __attribute__((ext_vector_type(8)));

__device__ __forceinline__ float bl0(float x) {
    return __int_as_float(__builtin_amdgcn_readfirstlane(__float_as_int(x)));
}
__device__ __forceinline__ float rlane(float x, int i) {
    return __int_as_float(__builtin_amdgcn_readlane(__float_as_int(x), i));
}

// In-register matvec: acc_lane = sum_i p_i * e[i], p_i broadcast via v_readlane
// (compile-time lane index). E held in ext_vector VALUES -> guaranteed VGPRs,
// no scratch. 4 independent FMA chains.
__device__ __forceinline__ float matvec64(float p, vf16 eA, vf16 eB, vf16 eC, vf16 eD) {
    float a0 = 0.f, a1 = 0.f, a2 = 0.f, a3 = 0.f;
    #pragma unroll
    for (int i = 0; i < 16; ++i) {
        a0 = fmaf(rlane(p, i     ), eA[i], a0);
        a1 = fmaf(rlane(p, i + 16), eB[i], a1);
        a2 = fmaf(rlane(p, i + 32), eC[i], a2);
        a3 = fmaf(rlane(p, i + 48), eD[i], a3);
    }
    return (a0 + a1) + (a2 + a3);
}

// Exact power-of-2 renormalization: scale state so lane0 lands in [1,2);
// accumulate the integer exponent in Lexp. All-scalar except one v_mul.
__device__ __forceinline__ float renorm(float sel, int& Lexp) {
    int bits = __float_as_int(bl0(sel)) & 0x7f800000;
    bits = bits < 0x00800000 ? 0x00800000 : bits;   // guard denormal/zero
    bits = bits > 0x7e800000 ? 0x7e800000 : bits;   // guard inf/huge
    Lexp += (bits >> 23) - 127;
    float scale = __int_as_float(0x7f000000 - bits); // 2^-(E-127), exact
    return sel * scale;
}

#define LOADF(EV, MV, g) do {                                              \
    const int sb_ = 1 + (g) * GRP;                                         \
    _Pragma("unroll")                                                      \
    for (int k_ = 0; k_ < GRP; ++k_) {                                     \
        EV[k_] = embase[(size_t)(sb_ + k_) * BB * TT];                     \
        MV[k_] = mkbase[(sb_ + k_) * BB];                                  \
    } } while (0)

#define STEPSF(EV, MV, lastg) do {                                         \
    vf8 Em_;                                                               \
    _Pragma("unroll")                                                      \
    for (int k_ = 0; k_ < GRP; ++k_) Em_[k_] = __expf(EV[k_]);             \
    _Pragma("unroll")                                                      \
    for (int k_ = 0; k_ < GRP; ++k_) {                                     \
        float acc_ = matvec64(p, eA, eB, eC, eD);                          \
        float t_   = acc_ * Em_[k_];                                       \
        int   mk_  = MV[k_];                                               \
        if (k_ == GRP - 1) mk_ = (lastg) ? 0 : mk_;  /* virtual step 256 */\
        float sel_ = mk_ ? t_ : p;                                         \
        p = renorm(sel_, Lexp);                                            \
    } } while (0)

#define LOADB(EV, MV, g) do {                                              \
    const int sb_ = 511 - (g) * GRP;                                       \
    _Pragma("unroll")                                                      \
    for (int k_ = 0; k_ < GRP; ++k_) {                                     \
        EV[k_] = embase[(size_t)(sb_ - k_) * BB * TT];                     \
        MV[k_] = mkbase[(sb_ - k_) * BB];                                  \
    } } while (0)

#define STEPSB(EV, MV) do {                                                \
    vf8 Em_;                                                               \
    _Pragma("unroll")                                                      \
    for (int k_ = 0; k_ < GRP; ++k_) Em_[k_] = __expf(EV[k_]);             \
    _Pragma("unroll")                                                      \
    for (int k_ = 0; k_ < GRP; ++k_) {                                     \
        float u_   = q * Em_[k_];                                          \
        float acc_ = matvec64(u_, eA, eB, eC, eD);                         \
        float sel_ = MV[k_] ? acc_ : q;                                    \
        q = renorm(sel_, Lexp);                                            \
    } } while (0)

// blocks [0,B): forward chains; [B,2B): backward chains; [2B,3B): numerator.
// One wave per block; (64,1) so the ~110 VGPRs stay resident (no spill).
__global__ __launch_bounds__(64, 1) void crf_chains(
    const float* __restrict__ em,      // S,B,T
    const int*   __restrict__ tags,    // S,B
    const int*   __restrict__ mask,    // S,B
    const float* __restrict__ start_t, // T
    const float* __restrict__ end_t,   // T
    const float* __restrict__ trans,   // T,T
    float* __restrict__ alpha_mid,     // B,T
    float* __restrict__ beta_mid,      // B,T
    float* __restrict__ num_ws)        // B
{
    const int lane = threadIdx.x;
    const int bid  = blockIdx.x;
    __shared__ float lds[TT * 65];     // bwd transpose staging only

    if (bid < BB) {
        // ------------- forward: alpha_0 .. alpha_255 (exp domain) -------------
        const int b = bid;
        const float* embase = em + (size_t)b * TT + lane;
        const int*   mkbase = mask + b;

        vf16 eA, eB, eC, eD;           // e[i] = exp(trans[i][lane]) : column of E
        #pragma unroll
        for (int i = 0; i < 16; ++i) {
            eA[i] = __expf(trans[(i     ) * TT + lane]);
            eB[i] = __expf(trans[(i + 16) * TT + lane]);
            eC[i] = __expf(trans[(i + 32) * TT + lane]);
            eD[i] = __expf(trans[(i + 48) * TT + lane]);
        }

        float av    = start_t[lane] + embase[0];
        float Lbase = bl0(av);
        float p     = __expf(av - Lbase);
        int   Lexp  = 0;

        vf8 em0, em1;
        vi8 mk0, mk1;

        LOADF(em0, mk0, 0);
        LOADF(em1, mk1, 1);
        for (int gg = 0; gg < 32; gg += 2) {
            STEPSF(em0, mk0, false);
            LOADF(em0, mk0, gg + 2);
            STEPSF(em1, mk1, gg + 1 == 31);
            LOADF(em1, mk1, gg + 3);
        }
        double a = (double)Lbase + (double)Lexp * 0.6931471805599453 + (double)__logf(p);
        alpha_mid[(size_t)b * TT + lane] = (float)a;

    } else if (bid < 2 * BB) {
        // ------------- backward: beta_511 .. beta_255 (exp domain) -------------
        const int b = bid - BB;
        const float* embase = em + (size_t)b * TT + lane;
        const int*   mkbase = mask + b;

        // row lane of E via LDS transpose (coalesced global, conflict-free LDS)
        for (int k = 0; k < TT; ++k)
            lds[k * 65 + lane] = trans[k * TT + lane];
        vf16 eA, eB, eC, eD;           // e[j] = exp(trans[lane][j]) : row of E
        #pragma unroll
        for (int j = 0; j < 16; ++j) {
            eA[j] = __expf(lds[lane * 65 + j     ]);
            eB[j] = __expf(lds[lane * 65 + j + 16]);
            eC[j] = __expf(lds[lane * 65 + j + 32]);
            eD[j] = __expf(lds[lane * 65 + j + 48]);
        }

        float q    = __expf(end_t[lane]);
        int   Lexp = 0;

        vf8 em0, em1;
        vi8 mk0, mk1;

        LOADB(em0, mk0, 0);
        LOADB(em1, mk1, 1);
        for (int gg = 0; gg < 32; gg += 2) {
            STEPSB(em0, mk0);
            LOADB(em0, mk0, gg + 2);
            STEPSB(em1, mk1);
            LOADB(em1, mk1, gg + 3);
        }
        double bsum = (double)Lexp * 0.6931471805599453 + (double)__logf(q);
        beta_mid[(size_t)b * TT + lane] = (float)bsum;

    } else {
        // ---------------- numerator (tag-path score) ----------------
        const int b = bid - 2 * BB;
        float local = 0.f;
        int   mcnt  = 0;
        for (int s = lane; s < SS; s += 64) {
            int tag = tags[s * BB + b];
            int mk  = mask[s * BB + b];
            mcnt += mk;
            if (s == 0) {
                local += start_t[tag] + em[(size_t)b * TT + tag];
            } else if (mk) {
                int tp = tags[(s - 1) * BB + b];
                local += trans[tp * TT + tag] + em[(size_t)s * BB * TT + (size_t)b * TT + tag];
            }
        }
        #pragma unroll
        for (int d = 32; d > 0; d >>= 1) {
            local += __shfl_down(local, d, 64);
            mcnt  += __shfl_down(mcnt, d, 64);
        }
        if (lane == 0) {
            int last = tags[(mcnt - 1) * BB + b];
            num_ws[b] = local + end_t[last];
        }
    }
}

// per-batch denominator + llh: 64 blocks x 8 waves, one wave per batch.
__global__ __launch_bounds__(512) void crf_llh(
    const float* __restrict__ alpha_mid,
    const float* __restrict__ beta_mid,
    const float* __restrict__ num_ws,
    float* __restrict__ llh)
{
    const int lane = threadIdx.x & 63;
    const int b    = blockIdx.x * 8 + (threadIdx.x >> 6);
    float v = alpha_mid[(size_t)b * TT + lane] + beta_mid[(size_t)b * TT + lane];
    float mx = v;
    #pragma unroll
    for (int d = 32; d > 0; d >>= 1) mx = fmaxf(mx, __shfl_xor(mx, d, 64));
    float s = __expf(v - mx);
    #pragma unroll
    for (int d = 32; d > 0; d >>= 1) s += __shfl_xor(s, d, 64);
    if (lane == 0) llh[b] = num_ws[b] - (mx + __logf(s));
}

__global__ __launch_bounds__(512) void crf_mean(const float* __restrict__ llh,
                                               float* __restrict__ out)
{
    const int t = threadIdx.x;
    float v = llh[t];
    #pragma unroll
    for (int d = 32; d > 0; d >>= 1) v += __shfl_down(v, d, 64);
    __shared__ float red[8];
    if ((t & 63) == 0) red[t >> 6] = v;
    __syncthreads();
    if (t == 0) {
        float s = 0.f;
        #pragma unroll
        for (int w = 0; w < 8; ++w) s += red[w];
        out[0] = s / (float)BB;
    }
}

extern "C" void kernel_launch(void* const* d_in, const int* in_sizes, int n_in,
                              void* d_out, int out_size, void* d_ws, size_t ws_size,
                              hipStream_t stream) {
    const float* em    = (const float*)d_in[0];
    const int*   tags  = (const int*)d_in[1];
    const int*   mask  = (const int*)d_in[2];
    const float* st    = (const float*)d_in[3];
    const float* en    = (const float*)d_in[4];
    const float* tr    = (const float*)d_in[5];

    float* ws        = (float*)d_ws;
    float* alpha_mid = ws;
    float* beta_mid  = ws + (size_t)BB * TT;
    float* num_ws    = ws + (size_t)2 * BB * TT;
    float* llh       = ws + (size_t)2 * BB * TT + BB;

    crf_chains<<<3 * BB, 64, 0, stream>>>(em, tags, mask, st, en, tr,
                                          alpha_mid, beta_mid, num_ws);
    crf_llh<<<BB / 8, 512, 0, stream>>>(alpha_mid, beta_mid, num_ws, llh);
    crf_mean<<<1, 512, 0, stream>>>(llh, (float*)d_out);
}